// Round 7
// baseline (75.019 us; speedup 1.0000x reference)
//
#include <hip/hip_runtime.h>

#define N_EP     4096     // 2048 lines * 2 endpoints
#define NLINES   2048
#define KPTS     2048
#define CCH      256
#define HC_      128
#define WC_      128
#define MAXNBR   16
#define NPTS_ALL 6144     // N_EP + KPTS
#define NBR_BLKS (N_EP / 16)    // 256
#define KP_BLKS  (KPTS / 16)    // 128

// ---- output chunk offsets (floats) ----
#define O_PTS  0          // all_points (1,6144,2)       12288
#define O_SC   12288      // all_scores (1,6144)          6144
#define O_DESC 18432      // all_descs (1,256,6144)    1572864
#define O_NL   1591296    // new_lines (1,2048,2,2)       8192
#define O_LJI  1599488    // lines_junc_idx (1,2048,2)    4096
#define O_LS   1603584    // ls (1,2048)                  2048

// ---- ws offsets (4-byte words) ----
#define W_LS   0          // float[2048]
#define W_DEG  2048       // int[4096]
#define W_NBR  6144       // int[4096*16]
#define W_KEEP 71680      // int[2048]
#define W_JUNC 73728      // float[8192] (x,y interleaved)
#define W_V    81920      // float[256*4096] unnormalized junction descs

// ============================================================================
// K_FRONT: input-only massively-parallel work, 16 points per block with the
// full endpoint set staged in LDS once per block (32 KB; L2 traffic 200->12MB).
// Thread layout: local_pt = t&15, stripe = t>>4 (256 candidates each).
// Lanes sharing a stripe read the SAME LDS word per step -> broadcast, no
// bank conflicts (4 distinct addresses per wave cycle).
//   blocks [0,256)    : neighbor lists of eps<=3 ball graph
//   blocks [256,384)  : keypoint suppression (r<4)
//   block  384        : ls normalize
// ============================================================================
__global__ __launch_bounds__(256) void k_front(
    const float2* __restrict__ ep, const float2* __restrict__ kpts,
    const float* __restrict__ ksc, const float* __restrict__ lsc,
    int* __restrict__ deg, int* __restrict__ nbr, int* __restrict__ keep_ws,
    float* __restrict__ ws_ls,
    float* __restrict__ out_pts, float* __restrict__ out_sc,
    float* __restrict__ out_ls) {
    __shared__ float2 s_ep[N_EP];     // 32 KB
    __shared__ int s_cnt[16];
    __shared__ float red[256];
    int b = blockIdx.x, t = threadIdx.x;

    if (b < NBR_BLKS + KP_BLKS) {
        for (int i = t; i < N_EP; i += 256) s_ep[i] = ep[i];
        if (t < 16) s_cnt[t] = 0;
        __syncthreads();
        int lp = t & 15, stripe = t >> 4;
        int j0 = stripe * 256;
        if (b < NBR_BLKS) {           // ---- neighbor lists ----
            int i = b * 16 + lp;
            float2 p = s_ep[i];
            for (int k = 0; k < 256; ++k) {
                int j = j0 + k;
                float2 q = s_ep[j];
                float dx = p.x - q.x, dy = p.y - q.y;
                if (j != i && dx * dx + dy * dy <= 9.0f) {
                    int s = atomicAdd(&s_cnt[lp], 1);
                    if (s < MAXNBR) nbr[i * MAXNBR + s] = j;
                }
            }
            __syncthreads();
            if (t < 16) deg[b * 16 + t] = min(s_cnt[t], MAXNBR);
        } else {                      // ---- keypoint suppression ----
            int kb = b - NBR_BLKS;
            int k = kb * 16 + lp;
            float2 p = kpts[k];
            int hit = 0;
            for (int q = 0; q < 256; ++q) {
                float2 e = s_ep[j0 + q];
                float dx = p.x - e.x, dy = p.y - e.y;
                if (dx * dx + dy * dy < 16.0f) hit = 1;
            }
            if (hit) atomicOr(&s_cnt[lp], 1);
            __syncthreads();
            if (t < 16) {
                int kk = kb * 16 + t;
                int keep = !s_cnt[t];
                float2 pk = kpts[kk];
                keep_ws[kk] = keep;
                out_pts[2 * (N_EP + kk)] = keep ? pk.x : 0.f;
                out_pts[2 * (N_EP + kk) + 1] = keep ? pk.y : 0.f;
                out_sc[N_EP + kk] = keep ? ksc[kk] : 0.f;
            }
        }
    } else {                          // ---- ls normalize ----
        float m = -1e30f;
        for (int i = t; i < NLINES; i += 256) m = fmaxf(m, lsc[i]);
        red[t] = m; __syncthreads();
        for (int s = 128; s > 0; s >>= 1) {
            if (t < s) red[t] = fmaxf(red[t], red[t + s]);
            __syncthreads();
        }
        float denom = 1e-8f + red[0];
        for (int i = t; i < NLINES; i += 256) {
            float v = lsc[i] / denom;
            ws_ls[i] = v;
            out_ls[i] = v;
        }
    }
}

// ============================================================================
// K_CLUSTER: single-block connected components on precomputed nbr lists +
// dense relabel + all junction outputs via LDS segment sums.
// Dynamic LDS (ints): lab[4096] rnk[4096] deg_s[4096] fcnt[4096] fsx[4096]
//                     fsy[4096] fss[4096]  = 112 KB
// ============================================================================
__global__ __launch_bounds__(1024) void k_cluster(
    const float2* __restrict__ ep, const int* __restrict__ deg,
    const int* __restrict__ nbr, const float* __restrict__ ws_ls,
    float* __restrict__ junc, float* __restrict__ out_pts,
    float* __restrict__ out_sc, float* __restrict__ out_nl,
    float* __restrict__ out_lji) {
    extern __shared__ int smem[];
    int*   lab   = smem;
    int*   rnk   = smem + N_EP;
    int*   deg_s = smem + 2 * N_EP;
    float* fcnt  = (float*)(smem + 3 * N_EP);
    float* fsx   = (float*)(smem + 4 * N_EP);
    float* fsy   = (float*)(smem + 5 * N_EP);
    float* fss   = (float*)(smem + 6 * N_EP);
    __shared__ int wsum[16];
    __shared__ int changed;

    int t = threadIdx.x;
    int lane = t & 63, wv = t >> 6;
    for (int i = t; i < N_EP; i += 1024) {
        lab[i] = i;
        deg_s[i] = deg[i];
        fcnt[i] = 0.f; fsx[i] = 0.f; fsy[i] = 0.f; fss[i] = 0.f;
    }
    // min-label propagation with pointer jumping
    for (int it = 0; it < 64; ++it) {
        __syncthreads();
        if (t == 0) changed = 0;
        __syncthreads();
        int f = 0;
        for (int i = t; i < N_EP; i += 1024) {
            int m = lab[i];
            int dg = deg_s[i];
            const int* nb = nbr + i * MAXNBR;
            for (int q = 0; q < dg; q++) m = min(m, lab[nb[q]]);
            m = min(m, lab[m]);           // pointer jump (lab[k] <= k invariant)
            if (m < lab[i]) { lab[i] = m; f = 1; }
        }
        if (f) atomicOr(&changed, 1);
        __syncthreads();
        if (changed == 0) break;
    }
    __syncthreads();
    // presence bitmap of roots -> dense rank via exclusive scan
    for (int i = t; i < N_EP; i += 1024) rnk[i] = 0;
    __syncthreads();
    for (int i = t; i < N_EP; i += 1024) rnk[lab[i]] = 1;
    __syncthreads();
    {
        int b4 = t * 4;
        int a0 = rnk[b4], a1 = rnk[b4 + 1], a2 = rnk[b4 + 2], a3 = rnk[b4 + 3];
        int s = a0 + a1 + a2 + a3;
        int v = s;
        for (int off = 1; off < 64; off <<= 1) {
            int u = __shfl_up(v, off);
            if (lane >= off) v += u;
        }
        if (lane == 63) wsum[wv] = v;
        __syncthreads();
        if (wv == 0 && lane < 16) {
            int w = wsum[lane];
            for (int off = 1; off < 16; off <<= 1) {
                int u = __shfl_up(w, off);
                if (lane >= off) w += u;
            }
            wsum[lane] = w;
        }
        __syncthreads();
        int excl = ((wv == 0) ? 0 : wsum[wv - 1]) + v - s;
        rnk[b4] = excl;
        rnk[b4 + 1] = excl + a0;
        rnk[b4 + 2] = excl + a0 + a1;
        rnk[b4 + 3] = excl + a0 + a1 + a2;
    }
    __syncthreads();
    // relabel + LDS segment sums
    for (int i = t; i < N_EP; i += 1024) {
        int c = rnk[lab[i]];
        out_lji[i] = (float)c;
        float2 p = ep[i];
        atomicAdd(&fcnt[c], 1.f);
        atomicAdd(&fsx[c], p.x);
        atomicAdd(&fsy[c], p.y);
        atomicAdd(&fss[c], ws_ls[i >> 1]);
        lab[i] = c;                       // lab now holds cluster id
    }
    __syncthreads();
    // segment means -> junction outputs
    for (int j = t; j < N_EP; j += 1024) {
        float cm = fmaxf(fcnt[j], 1.f);
        float jx = fsx[j] / cm, jy = fsy[j] / cm;
        fsx[j] = jx; fsy[j] = jy;
        junc[2 * j] = jx; junc[2 * j + 1] = jy;
        out_pts[2 * j] = jx; out_pts[2 * j + 1] = jy;
        out_sc[j] = fss[j] / cm;
    }
    __syncthreads();
    // new_lines = junctions[clusters]
    for (int e = t; e < N_EP; e += 1024) {
        int c = lab[e];
        out_nl[2 * e] = fsx[c];
        out_nl[2 * e + 1] = fsy[c];
    }
}

// ============================================================================
// K_SAMP: blocks [0,256): bilinear sample, 1 block/channel, plane in LDS
// (input read exactly once), no atomics. Blocks [256,384): float4 masked
// copy of keypoint descriptors.
// ============================================================================
__global__ __launch_bounds__(1024) void k_samp(const float* __restrict__ ad,
                                               const float* __restrict__ junc,
                                               const float* __restrict__ desc,
                                               const int* __restrict__ keep,
                                               float* __restrict__ v_ws,
                                               float* __restrict__ out_desc) {
    __shared__ float plane[HC_ * WC_];   // 64 KB
    int b = blockIdx.x, t = threadIdx.x;
    if (b < CCH) {
        int c = b;
        const float4* s4 = (const float4*)(ad + c * (HC_ * WC_));
        float4* p4 = (float4*)plane;
        #pragma unroll
        for (int i = 0; i < 4; ++i) p4[t + i * 1024] = s4[t + i * 1024];
        __syncthreads();
        const float2* j2 = (const float2*)junc;
        #pragma unroll
        for (int k = 0; k < 4; ++k) {
            int m = t + k * 1024;
            float2 pj = j2[m];
            float x = (pj.x - 3.5f) * (127.0f / 1019.5f);
            float y = (pj.y - 3.5f) * (127.0f / 1019.5f);
            float x0f = fminf(fmaxf(floorf(x), 0.f), WC_ - 1);
            float y0f = fminf(fmaxf(floorf(y), 0.f), HC_ - 1);
            float x1f = fminf(x0f + 1.f, WC_ - 1);
            float y1f = fminf(y0f + 1.f, HC_ - 1);
            float wx = x - x0f, wy = y - y0f;
            int x0 = (int)x0f, x1 = (int)x1f, y0 = (int)y0f, y1 = (int)y1f;
            float v = plane[y0 * WC_ + x0] * (1.f - wx) * (1.f - wy)
                    + plane[y0 * WC_ + x1] * wx * (1.f - wy)
                    + plane[y1 * WC_ + x0] * (1.f - wx) * wy
                    + plane[y1 * WC_ + x1] * wx * wy;
            v_ws[c * N_EP + m] = v;
        }
    } else {
        int gid = (b - CCH) * 1024 + t;      // 131072 float4 groups
        int c = gid >> 9;                    // 512 groups per channel
        int k4 = (gid & 511) * 4;
        float4 d = *(const float4*)(desc + c * KPTS + k4);
        float4 o;
        o.x = keep[k4]     ? d.x : 0.f;
        o.y = keep[k4 + 1] ? d.y : 0.f;
        o.z = keep[k4 + 2] ? d.z : 0.f;
        o.w = keep[k4 + 3] ? d.w : 0.f;
        *(float4*)(out_desc + c * NPTS_ALL + N_EP + k4) = o;
    }
}

// ============================================================================
// K_EPI: 64 blocks; 256ch x 64junc LDS tile — column norms + normalize,
// fully coalesced, no atomics.
// ============================================================================
__global__ __launch_bounds__(256) void k_epi(const float* __restrict__ v_ws,
                                             float* __restrict__ out_desc) {
    __shared__ float tile[CCH][64];
    __shared__ float partial[4][64];
    __shared__ float inv[64];
    int b = blockIdx.x, t = threadIdx.x;
    int m0 = b * 64;
    int q = t >> 6, ml = t & 63;
    for (int cc = 0; cc < 64; ++cc) {
        int c = cc * 4 + q;
        tile[c][ml] = v_ws[c * N_EP + m0 + ml];
    }
    __syncthreads();
    float s = 0.f;
    for (int c = q * 64; c < q * 64 + 64; ++c) {
        float v = tile[c][ml];
        s += v * v;
    }
    partial[q][ml] = s;
    __syncthreads();
    if (t < 64) {
        float tot = partial[0][t] + partial[1][t] + partial[2][t] + partial[3][t];
        inv[t] = 1.f / fmaxf(sqrtf(tot), 1e-12f);
    }
    __syncthreads();
    for (int cc = 0; cc < 64; ++cc) {
        int c = cc * 4 + q;
        out_desc[c * NPTS_ALL + m0 + ml] = tile[c][ml] * inv[ml];
    }
}

extern "C" void kernel_launch(void* const* d_in, const int* in_sizes, int n_in,
                              void* d_out, int out_size, void* d_ws, size_t ws_size,
                              hipStream_t stream) {
    const float* lines    = (const float*)d_in[0];   // (1,2048,2,2) == endpoints (4096,2)
    const float* lscores  = (const float*)d_in[1];   // (1,2048)
    const float* kpts     = (const float*)d_in[2];   // (1,2048,2)
    const float* kscores  = (const float*)d_in[3];   // (1,2048)
    const float* descs    = (const float*)d_in[4];   // (1,256,2048)
    const float* alldesc  = (const float*)d_in[5];   // (1,256,128,128)
    float* out = (float*)d_out;

    float* wf   = (float*)d_ws;
    int*   wi   = (int*)d_ws;
    float* ws_ls = wf + W_LS;
    int*   deg   = wi + W_DEG;
    int*   nbr   = wi + W_NBR;
    int*   keep  = wi + W_KEEP;
    float* junc  = wf + W_JUNC;
    float* v_ws  = wf + W_V;

    k_front<<<NBR_BLKS + KP_BLKS + 1, 256, 0, stream>>>(
        (const float2*)lines, (const float2*)kpts, kscores, lscores,
        deg, nbr, keep, ws_ls, out + O_PTS, out + O_SC, out + O_LS);

    size_t lds_bytes = (size_t)(7 * N_EP) * sizeof(int);   // 112 KB
    k_cluster<<<1, 1024, lds_bytes, stream>>>(
        (const float2*)lines, deg, nbr, ws_ls, junc,
        out + O_PTS, out + O_SC, out + O_NL, out + O_LJI);

    k_samp<<<CCH + 128, 1024, 0, stream>>>(alldesc, junc, descs, keep, v_ws,
                                           out + O_DESC);

    k_epi<<<64, 256, 0, stream>>>(v_ws, out + O_DESC);
}

// Round 8
// 67.956 us; speedup vs baseline: 1.1039x; 1.1039x over previous
//
#include <hip/hip_runtime.h>

#define N_EP     4096     // 2048 lines * 2 endpoints
#define NLINES   2048
#define KPTS     2048
#define CCH      256
#define HC_      128
#define WC_      128
#define MAXNBR   16
#define NPTS_ALL 6144     // N_EP + KPTS
#define PPB      4                    // points per k_front block
#define NBR_BLKS (N_EP / PPB)         // 1024
#define KP_BLKS  (KPTS / PPB)         // 512

// ---- output chunk offsets (floats) ----
#define O_PTS  0          // all_points (1,6144,2)       12288
#define O_SC   12288      // all_scores (1,6144)          6144
#define O_DESC 18432      // all_descs (1,256,6144)    1572864
#define O_NL   1591296    // new_lines (1,2048,2,2)       8192
#define O_LJI  1599488    // lines_junc_idx (1,2048,2)    4096
#define O_LS   1603584    // ls (1,2048)                  2048

// ---- ws offsets (4-byte words) ----
#define W_LS   0          // float[2048]
#define W_DEG  2048       // int[4096]
#define W_NBR  6144       // int[4096*16]
#define W_KEEP 71680      // int[2048]
#define W_JUNC 73728      // float[8192] (x,y interleaved)
#define W_V    81920      // float[256*4096] unnormalized junction descs

// ============================================================================
// K_FRONT: input-only massively-parallel work. 4 points per block, endpoint
// set staged in LDS (32 KB). 1537 blocks (~5-6/CU, ~20 waves/CU) keeps
// latency hidden while cutting L2 traffic 200->48 MB (R7 lesson: 16 pts/blk
// collapsed occupancy). Layout: lp = t&3, stripe = t>>2; the 4 lanes of a
// group broadcast-read the same LDS word (no bank conflicts).
//   blocks [0,1024)     : neighbor lists of eps<=3 ball graph
//   blocks [1024,1536)  : keypoint suppression (r<4)
//   block  1536         : ls normalize
// ============================================================================
__global__ __launch_bounds__(256) void k_front(
    const float2* __restrict__ ep, const float2* __restrict__ kpts,
    const float* __restrict__ ksc, const float* __restrict__ lsc,
    int* __restrict__ deg, int* __restrict__ nbr, int* __restrict__ keep_ws,
    float* __restrict__ ws_ls,
    float* __restrict__ out_pts, float* __restrict__ out_sc,
    float* __restrict__ out_ls) {
    __shared__ float2 s_ep[N_EP];     // 32 KB
    __shared__ int s_cnt[PPB];
    __shared__ float red[256];
    int b = blockIdx.x, t = threadIdx.x;

    if (b < NBR_BLKS + KP_BLKS) {
        for (int i = t; i < N_EP; i += 256) s_ep[i] = ep[i];
        if (t < PPB) s_cnt[t] = 0;
        __syncthreads();
        int lp = t & (PPB - 1), stripe = t >> 2;      // 64 stripes
        int j0 = stripe * (N_EP / 64);                // 64 candidates each
        if (b < NBR_BLKS) {           // ---- neighbor lists ----
            int i = b * PPB + lp;
            float2 p = s_ep[i];
            #pragma unroll 4
            for (int k = 0; k < N_EP / 64; ++k) {
                int j = j0 + k;
                float2 q = s_ep[j];
                float dx = p.x - q.x, dy = p.y - q.y;
                if (j != i && dx * dx + dy * dy <= 9.0f) {
                    int s = atomicAdd(&s_cnt[lp], 1);
                    if (s < MAXNBR) nbr[i * MAXNBR + s] = j;
                }
            }
            __syncthreads();
            if (t < PPB) deg[b * PPB + t] = min(s_cnt[t], MAXNBR);
        } else {                      // ---- keypoint suppression ----
            int kb = b - NBR_BLKS;
            int k = kb * PPB + lp;
            float2 p = kpts[k];
            int hit = 0;
            #pragma unroll 4
            for (int q = 0; q < N_EP / 64; ++q) {
                float2 e = s_ep[j0 + q];
                float dx = p.x - e.x, dy = p.y - e.y;
                if (dx * dx + dy * dy < 16.0f) hit = 1;
            }
            if (hit) atomicOr(&s_cnt[lp], 1);
            __syncthreads();
            if (t < PPB) {
                int kk = kb * PPB + t;
                int keep = !s_cnt[t];
                float2 pk = kpts[kk];
                keep_ws[kk] = keep;
                out_pts[2 * (N_EP + kk)] = keep ? pk.x : 0.f;
                out_pts[2 * (N_EP + kk) + 1] = keep ? pk.y : 0.f;
                out_sc[N_EP + kk] = keep ? ksc[kk] : 0.f;
            }
        }
    } else {                          // ---- ls normalize ----
        float m = -1e30f;
        for (int i = t; i < NLINES; i += 256) m = fmaxf(m, lsc[i]);
        red[t] = m; __syncthreads();
        for (int s = 128; s > 0; s >>= 1) {
            if (t < s) red[t] = fmaxf(red[t], red[t + s]);
            __syncthreads();
        }
        float denom = 1e-8f + red[0];
        for (int i = t; i < NLINES; i += 256) {
            float v = lsc[i] / denom;
            ws_ls[i] = v;
            out_ls[i] = v;
        }
    }
}

// ============================================================================
// K_CLUSTER: single-block connected components on precomputed nbr lists +
// dense relabel + all junction outputs via LDS segment sums.
// Dynamic LDS (ints): lab[4096] rnk[4096] deg_s[4096] fcnt[4096] fsx[4096]
//                     fsy[4096] fss[4096]  = 112 KB
// ============================================================================
__global__ __launch_bounds__(1024) void k_cluster(
    const float2* __restrict__ ep, const int* __restrict__ deg,
    const int* __restrict__ nbr, const float* __restrict__ ws_ls,
    float* __restrict__ junc, float* __restrict__ out_pts,
    float* __restrict__ out_sc, float* __restrict__ out_nl,
    float* __restrict__ out_lji) {
    extern __shared__ int smem[];
    int*   lab   = smem;
    int*   rnk   = smem + N_EP;
    int*   deg_s = smem + 2 * N_EP;
    float* fcnt  = (float*)(smem + 3 * N_EP);
    float* fsx   = (float*)(smem + 4 * N_EP);
    float* fsy   = (float*)(smem + 5 * N_EP);
    float* fss   = (float*)(smem + 6 * N_EP);
    __shared__ int wsum[16];
    __shared__ int changed;

    int t = threadIdx.x;
    int lane = t & 63, wv = t >> 6;
    for (int i = t; i < N_EP; i += 1024) {
        lab[i] = i;
        deg_s[i] = deg[i];
        fcnt[i] = 0.f; fsx[i] = 0.f; fsy[i] = 0.f; fss[i] = 0.f;
    }
    // min-label propagation with pointer jumping
    for (int it = 0; it < 64; ++it) {
        __syncthreads();
        if (t == 0) changed = 0;
        __syncthreads();
        int f = 0;
        for (int i = t; i < N_EP; i += 1024) {
            int m = lab[i];
            int dg = deg_s[i];
            const int* nb = nbr + i * MAXNBR;
            for (int q = 0; q < dg; q++) m = min(m, lab[nb[q]]);
            m = min(m, lab[m]);           // pointer jump (lab[k] <= k invariant)
            if (m < lab[i]) { lab[i] = m; f = 1; }
        }
        if (f) atomicOr(&changed, 1);
        __syncthreads();
        if (changed == 0) break;
    }
    __syncthreads();
    // presence bitmap of roots -> dense rank via exclusive scan
    for (int i = t; i < N_EP; i += 1024) rnk[i] = 0;
    __syncthreads();
    for (int i = t; i < N_EP; i += 1024) rnk[lab[i]] = 1;
    __syncthreads();
    {
        int b4 = t * 4;
        int a0 = rnk[b4], a1 = rnk[b4 + 1], a2 = rnk[b4 + 2], a3 = rnk[b4 + 3];
        int s = a0 + a1 + a2 + a3;
        int v = s;
        for (int off = 1; off < 64; off <<= 1) {
            int u = __shfl_up(v, off);
            if (lane >= off) v += u;
        }
        if (lane == 63) wsum[wv] = v;
        __syncthreads();
        if (wv == 0 && lane < 16) {
            int w = wsum[lane];
            for (int off = 1; off < 16; off <<= 1) {
                int u = __shfl_up(w, off);
                if (lane >= off) w += u;
            }
            wsum[lane] = w;
        }
        __syncthreads();
        int excl = ((wv == 0) ? 0 : wsum[wv - 1]) + v - s;
        rnk[b4] = excl;
        rnk[b4 + 1] = excl + a0;
        rnk[b4 + 2] = excl + a0 + a1;
        rnk[b4 + 3] = excl + a0 + a1 + a2;
    }
    __syncthreads();
    // relabel + LDS segment sums
    for (int i = t; i < N_EP; i += 1024) {
        int c = rnk[lab[i]];
        out_lji[i] = (float)c;
        float2 p = ep[i];
        atomicAdd(&fcnt[c], 1.f);
        atomicAdd(&fsx[c], p.x);
        atomicAdd(&fsy[c], p.y);
        atomicAdd(&fss[c], ws_ls[i >> 1]);
        lab[i] = c;                       // lab now holds cluster id
    }
    __syncthreads();
    // segment means -> junction outputs
    for (int j = t; j < N_EP; j += 1024) {
        float cm = fmaxf(fcnt[j], 1.f);
        float jx = fsx[j] / cm, jy = fsy[j] / cm;
        fsx[j] = jx; fsy[j] = jy;
        junc[2 * j] = jx; junc[2 * j + 1] = jy;
        out_pts[2 * j] = jx; out_pts[2 * j + 1] = jy;
        out_sc[j] = fss[j] / cm;
    }
    __syncthreads();
    // new_lines = junctions[clusters]
    for (int e = t; e < N_EP; e += 1024) {
        int c = lab[e];
        out_nl[2 * e] = fsx[c];
        out_nl[2 * e + 1] = fsy[c];
    }
}

// ============================================================================
// K_SAMP: blocks [0,256): bilinear sample, 1 block/channel, plane in LDS
// (input read exactly once), no atomics. Blocks [256,384): float4 masked
// copy of keypoint descriptors.
// ============================================================================
__global__ __launch_bounds__(1024) void k_samp(const float* __restrict__ ad,
                                               const float* __restrict__ junc,
                                               const float* __restrict__ desc,
                                               const int* __restrict__ keep,
                                               float* __restrict__ v_ws,
                                               float* __restrict__ out_desc) {
    __shared__ float plane[HC_ * WC_];   // 64 KB
    int b = blockIdx.x, t = threadIdx.x;
    if (b < CCH) {
        int c = b;
        const float4* s4 = (const float4*)(ad + c * (HC_ * WC_));
        float4* p4 = (float4*)plane;
        #pragma unroll
        for (int i = 0; i < 4; ++i) p4[t + i * 1024] = s4[t + i * 1024];
        __syncthreads();
        const float2* j2 = (const float2*)junc;
        #pragma unroll
        for (int k = 0; k < 4; ++k) {
            int m = t + k * 1024;
            float2 pj = j2[m];
            float x = (pj.x - 3.5f) * (127.0f / 1019.5f);
            float y = (pj.y - 3.5f) * (127.0f / 1019.5f);
            float x0f = fminf(fmaxf(floorf(x), 0.f), WC_ - 1);
            float y0f = fminf(fmaxf(floorf(y), 0.f), HC_ - 1);
            float x1f = fminf(x0f + 1.f, WC_ - 1);
            float y1f = fminf(y0f + 1.f, HC_ - 1);
            float wx = x - x0f, wy = y - y0f;
            int x0 = (int)x0f, x1 = (int)x1f, y0 = (int)y0f, y1 = (int)y1f;
            float v = plane[y0 * WC_ + x0] * (1.f - wx) * (1.f - wy)
                    + plane[y0 * WC_ + x1] * wx * (1.f - wy)
                    + plane[y1 * WC_ + x0] * (1.f - wx) * wy
                    + plane[y1 * WC_ + x1] * wx * wy;
            v_ws[c * N_EP + m] = v;
        }
    } else {
        int gid = (b - CCH) * 1024 + t;      // 131072 float4 groups
        int c = gid >> 9;                    // 512 groups per channel
        int k4 = (gid & 511) * 4;
        float4 d = *(const float4*)(desc + c * KPTS + k4);
        float4 o;
        o.x = keep[k4]     ? d.x : 0.f;
        o.y = keep[k4 + 1] ? d.y : 0.f;
        o.z = keep[k4 + 2] ? d.z : 0.f;
        o.w = keep[k4 + 3] ? d.w : 0.f;
        *(float4*)(out_desc + c * NPTS_ALL + N_EP + k4) = o;
    }
}

// ============================================================================
// K_EPI: 64 blocks; 256ch x 64junc LDS tile — column norms + normalize,
// fully coalesced, no atomics.
// ============================================================================
__global__ __launch_bounds__(256) void k_epi(const float* __restrict__ v_ws,
                                             float* __restrict__ out_desc) {
    __shared__ float tile[CCH][64];
    __shared__ float partial[4][64];
    __shared__ float inv[64];
    int b = blockIdx.x, t = threadIdx.x;
    int m0 = b * 64;
    int q = t >> 6, ml = t & 63;
    for (int cc = 0; cc < 64; ++cc) {
        int c = cc * 4 + q;
        tile[c][ml] = v_ws[c * N_EP + m0 + ml];
    }
    __syncthreads();
    float s = 0.f;
    for (int c = q * 64; c < q * 64 + 64; ++c) {
        float v = tile[c][ml];
        s += v * v;
    }
    partial[q][ml] = s;
    __syncthreads();
    if (t < 64) {
        float tot = partial[0][t] + partial[1][t] + partial[2][t] + partial[3][t];
        inv[t] = 1.f / fmaxf(sqrtf(tot), 1e-12f);
    }
    __syncthreads();
    for (int cc = 0; cc < 64; ++cc) {
        int c = cc * 4 + q;
        out_desc[c * NPTS_ALL + m0 + ml] = tile[c][ml] * inv[ml];
    }
}

extern "C" void kernel_launch(void* const* d_in, const int* in_sizes, int n_in,
                              void* d_out, int out_size, void* d_ws, size_t ws_size,
                              hipStream_t stream) {
    const float* lines    = (const float*)d_in[0];   // (1,2048,2,2) == endpoints (4096,2)
    const float* lscores  = (const float*)d_in[1];   // (1,2048)
    const float* kpts     = (const float*)d_in[2];   // (1,2048,2)
    const float* kscores  = (const float*)d_in[3];   // (1,2048)
    const float* descs    = (const float*)d_in[4];   // (1,256,2048)
    const float* alldesc  = (const float*)d_in[5];   // (1,256,128,128)
    float* out = (float*)d_out;

    float* wf   = (float*)d_ws;
    int*   wi   = (int*)d_ws;
    float* ws_ls = wf + W_LS;
    int*   deg   = wi + W_DEG;
    int*   nbr   = wi + W_NBR;
    int*   keep  = wi + W_KEEP;
    float* junc  = wf + W_JUNC;
    float* v_ws  = wf + W_V;

    k_front<<<NBR_BLKS + KP_BLKS + 1, 256, 0, stream>>>(
        (const float2*)lines, (const float2*)kpts, kscores, lscores,
        deg, nbr, keep, ws_ls, out + O_PTS, out + O_SC, out + O_LS);

    size_t lds_bytes = (size_t)(7 * N_EP) * sizeof(int);   // 112 KB
    k_cluster<<<1, 1024, lds_bytes, stream>>>(
        (const float2*)lines, deg, nbr, ws_ls, junc,
        out + O_PTS, out + O_SC, out + O_NL, out + O_LJI);

    k_samp<<<CCH + 128, 1024, 0, stream>>>(alldesc, junc, descs, keep, v_ws,
                                           out + O_DESC);

    k_epi<<<64, 256, 0, stream>>>(v_ws, out + O_DESC);
}